// Round 1
// baseline (279.710 us; speedup 1.0000x reference)
//
#include <hip/hip_runtime.h>

// Problem constants
#define BATCH 2
#define NSEQ 2304       // 48*48
#define DIM 768
#define HEADS 12
#define HD 64
#define M_TOK (BATCH * NSEQ)   // 4608
#define LDSP 72                // padded LDS row stride (bf16 elems): 144 B, 16B-aligned, 4-bank rotate

typedef __attribute__((ext_vector_type(8))) short bf16x8;
typedef __attribute__((ext_vector_type(4))) float f32x4;

__device__ __forceinline__ short f2bf(float f) {
    union { float f; unsigned u; } v; v.f = f;
    unsigned r = v.u + 0x7fffu + ((v.u >> 16) & 1u);
    return (short)(r >> 16);
}
__device__ __forceinline__ float bf2f(short s) {
    union { unsigned u; float f; } v; v.u = ((unsigned)(unsigned short)s) << 16;
    return v.f;
}

// ---------------- fp32 -> bf16 conversion (4 elems/thread) ----------------
__global__ void cvt_bf16_kernel(const float* __restrict__ in, short* __restrict__ out, int n4) {
    int i = blockIdx.x * 256 + threadIdx.x;
    if (i < n4) {
        float4 v = reinterpret_cast<const float4*>(in)[i];
        short4 o;
        o.x = f2bf(v.x); o.y = f2bf(v.y); o.z = f2bf(v.z); o.w = f2bf(v.w);
        reinterpret_cast<short4*>(out)[i] = o;
    }
}

// ---------------- qkv GEMM: [4608,768] x [2304,768]^T + bias ----------------
// scatters q,k -> [b,h,tok,d] bf16 ; v -> [b,h,d,tok] bf16 (transposed)
__global__ __launch_bounds__(256) void gemm_qkv_kernel(
    const short* __restrict__ A,    // xb [4608,768]
    const short* __restrict__ Bt,   // wqkvb [2304,768]
    const float* __restrict__ bias, // [2304]
    short* __restrict__ qb, short* __restrict__ kbuf, short* __restrict__ vtb)
{
    __shared__ __align__(16) short At[64 * LDSP];
    __shared__ __align__(16) short Bl[64 * LDSP];
    const int m0 = blockIdx.x * 64, n0 = blockIdx.y * 64;
    const int tid = threadIdx.x, lane = tid & 63, wave = tid >> 6;
    const int quad = lane >> 4, l16 = lane & 15;
    const int wm = (wave >> 1) * 32, wn = (wave & 1) * 32;
    const int r = tid >> 2, cs = (tid & 3) * 16;
    f32x4 acc[2][2] = {};

    for (int k0 = 0; k0 < DIM; k0 += 64) {
        const uint4* ga = reinterpret_cast<const uint4*>(&A[(size_t)(m0 + r) * DIM + k0 + cs]);
        uint4* sa = reinterpret_cast<uint4*>(&At[r * LDSP + cs]);
        sa[0] = ga[0]; sa[1] = ga[1];
        const uint4* gb = reinterpret_cast<const uint4*>(&Bt[(size_t)(n0 + r) * DIM + k0 + cs]);
        uint4* sb = reinterpret_cast<uint4*>(&Bl[r * LDSP + cs]);
        sb[0] = gb[0]; sb[1] = gb[1];
        __syncthreads();
#pragma unroll
        for (int ks = 0; ks < 2; ++ks) {
            bf16x8 af[2], bf[2];
#pragma unroll
            for (int mt = 0; mt < 2; ++mt)
                af[mt] = *reinterpret_cast<const bf16x8*>(&At[(wm + mt * 16 + l16) * LDSP + ks * 32 + quad * 8]);
#pragma unroll
            for (int nt = 0; nt < 2; ++nt)
                bf[nt] = *reinterpret_cast<const bf16x8*>(&Bl[(wn + nt * 16 + l16) * LDSP + ks * 32 + quad * 8]);
#pragma unroll
            for (int mt = 0; mt < 2; ++mt)
#pragma unroll
                for (int nt = 0; nt < 2; ++nt)
                    acc[mt][nt] = __builtin_amdgcn_mfma_f32_16x16x32_bf16(af[mt], bf[nt], acc[mt][nt], 0, 0, 0);
        }
        __syncthreads();
    }

    const int which = n0 / DIM;          // 0=q 1=k 2=v
    const int head = (n0 % DIM) / HD;
    const int b = m0 / NSEQ;             // NSEQ % 64 == 0 -> constant per block
    const int tokb = m0 % NSEQ;
#pragma unroll
    for (int mt = 0; mt < 2; ++mt) {
#pragma unroll
        for (int nt = 0; nt < 2; ++nt) {
            const int n = n0 + wn + nt * 16 + l16;
            const int d = wn + nt * 16 + l16;
            const float bi = bias[n];
            const int tok0 = tokb + wm + mt * 16 + quad * 4;
            if (which == 2) {
                short4 pv;
                pv.x = f2bf(acc[mt][nt][0] + bi);
                pv.y = f2bf(acc[mt][nt][1] + bi);
                pv.z = f2bf(acc[mt][nt][2] + bi);
                pv.w = f2bf(acc[mt][nt][3] + bi);
                *reinterpret_cast<short4*>(&vtb[((size_t)(b * HEADS + head) * HD + d) * NSEQ + tok0]) = pv;
            } else {
                short* dst = (which == 0) ? qb : kbuf;
#pragma unroll
                for (int rg = 0; rg < 4; ++rg)
                    dst[((size_t)(b * HEADS + head) * NSEQ + tok0 + rg) * HD + d] =
                        f2bf(acc[mt][nt][rg] + bi);
            }
        }
    }
}

// ---------------- RoPE in-place on q,k [bh, tok, 64] ----------------
__global__ void rope_kernel(short* __restrict__ qb, short* __restrict__ kb) {
    int idx = blockIdx.x * 256 + threadIdx.x;  // total 24*2304*32
    if (idx >= BATCH * HEADS * NSEQ * 32) return;
    const int i = idx & 31;
    const int tok = (idx >> 5) % NSEQ;
    const int bh = idx / (32 * NSEQ);
    const int y = tok / 48, x = tok % 48;
    const int pi = (i < 16) ? i : (i - 16);
    const float coord = (i < 16) ? (2.0f * (y + 0.5f) / 48.0f - 1.0f)
                                 : (2.0f * (x + 0.5f) / 48.0f - 1.0f);
    const float period = powf(100.0f, (float)pi * (1.0f / 16.0f));
    const float ang = 2.0f * 3.14159265358979323846f * coord / period;
    const float s = sinf(ang), c = cosf(ang);
    const size_t base = ((size_t)bh * NSEQ + tok) * HD;
    float q1 = bf2f(qb[base + i]), q2 = bf2f(qb[base + i + 32]);
    qb[base + i]      = f2bf(q1 * c - q2 * s);
    qb[base + i + 32] = f2bf(q2 * c + q1 * s);
    float k1 = bf2f(kb[base + i]), k2 = bf2f(kb[base + i + 32]);
    kb[base + i]      = f2bf(k1 * c - k2 * s);
    kb[base + i + 32] = f2bf(k2 * c + k1 * s);
}

// ---------------- flash attention ----------------
// grid (36, 12, 2), block 256. Each block: 64 q-rows for one (b,h).
__global__ __launch_bounds__(256) void attn_kernel(
    const short* __restrict__ qb, const short* __restrict__ kb,
    const short* __restrict__ vtb, short* __restrict__ ob)
{
    __shared__ __align__(16) short Kt[64 * LDSP];
    __shared__ __align__(16) short Vt[64 * LDSP];
    __shared__ __align__(16) short Pl[4 * 16 * LDSP];
    const int qt = blockIdx.x, h = blockIdx.y, b = blockIdx.z;
    const int bh = b * HEADS + h;
    const int tid = threadIdx.x, lane = tid & 63, wave = tid >> 6;
    const int quad = lane >> 4, l16 = lane & 15;
    const int q0 = qt * 64;
    const short* qbase = qb + (size_t)bh * NSEQ * HD;
    const short* kbase = kb + (size_t)bh * NSEQ * HD;
    const short* vbase = vtb + (size_t)bh * HD * NSEQ;

    bf16x8 qf[2];
#pragma unroll
    for (int ks = 0; ks < 2; ++ks)
        qf[ks] = *reinterpret_cast<const bf16x8*>(
            &qbase[(size_t)(q0 + wave * 16 + l16) * HD + ks * 32 + quad * 8]);

    float m_i[4], l_i[4];
    f32x4 oacc[4] = {};
#pragma unroll
    for (int rg = 0; rg < 4; ++rg) { m_i[rg] = -1e30f; l_i[rg] = 0.f; }

    const int r = tid >> 2, cs = (tid & 3) * 16;
    short* pw = &Pl[wave * 16 * LDSP];

    for (int kt = 0; kt < NSEQ / 64; ++kt) {
        const int kb0 = kt * 64;
        const uint4* gk = reinterpret_cast<const uint4*>(&kbase[(size_t)(kb0 + r) * HD + cs]);
        uint4* sk = reinterpret_cast<uint4*>(&Kt[r * LDSP + cs]);
        sk[0] = gk[0]; sk[1] = gk[1];
        const uint4* gv = reinterpret_cast<const uint4*>(&vbase[(size_t)r * NSEQ + kb0 + cs]);
        uint4* sv = reinterpret_cast<uint4*>(&Vt[r * LDSP + cs]);
        sv[0] = gv[0]; sv[1] = gv[1];
        __syncthreads();

        // S = Q K^T  (rows: quad*4+reg, cols: nt*16+l16)
        f32x4 sacc[4] = {};
#pragma unroll
        for (int ks = 0; ks < 2; ++ks) {
#pragma unroll
            for (int nt = 0; nt < 4; ++nt) {
                bf16x8 kf = *reinterpret_cast<const bf16x8*>(
                    &Kt[(nt * 16 + l16) * LDSP + ks * 32 + quad * 8]);
                sacc[nt] = __builtin_amdgcn_mfma_f32_16x16x32_bf16(qf[ks], kf, sacc[nt], 0, 0, 0);
            }
        }
#pragma unroll
        for (int nt = 0; nt < 4; ++nt) sacc[nt] *= 0.125f;  // 1/sqrt(64)

        float mnew[4], alpha[4];
#pragma unroll
        for (int rg = 0; rg < 4; ++rg) {
            float mx = fmaxf(fmaxf(sacc[0][rg], sacc[1][rg]), fmaxf(sacc[2][rg], sacc[3][rg]));
#pragma unroll
            for (int off = 1; off < 16; off <<= 1) mx = fmaxf(mx, __shfl_xor(mx, off, 64));
            float mn = fmaxf(m_i[rg], mx);
            mnew[rg] = mn;
            alpha[rg] = __expf(m_i[rg] - mn);
        }
        float rs[4] = {0.f, 0.f, 0.f, 0.f};
#pragma unroll
        for (int nt = 0; nt < 4; ++nt)
#pragma unroll
            for (int rg = 0; rg < 4; ++rg) {
                float p = __expf(sacc[nt][rg] - mnew[rg]);
                sacc[nt][rg] = p;
                rs[rg] += p;
            }
#pragma unroll
        for (int rg = 0; rg < 4; ++rg) {
#pragma unroll
            for (int off = 1; off < 16; off <<= 1) rs[rg] += __shfl_xor(rs[rg], off, 64);
            l_i[rg] = l_i[rg] * alpha[rg] + rs[rg];
            m_i[rg] = mnew[rg];
        }
#pragma unroll
        for (int dt = 0; dt < 4; ++dt)
#pragma unroll
            for (int rg = 0; rg < 4; ++rg) oacc[dt][rg] *= alpha[rg];

        // P: C-layout -> LDS -> A-layout (bf16)
#pragma unroll
        for (int nt = 0; nt < 4; ++nt)
#pragma unroll
            for (int rg = 0; rg < 4; ++rg)
                pw[(quad * 4 + rg) * LDSP + nt * 16 + l16] = f2bf(sacc[nt][rg]);
        __syncthreads();

#pragma unroll
        for (int ks = 0; ks < 2; ++ks) {
            bf16x8 pf = *reinterpret_cast<const bf16x8*>(&pw[l16 * LDSP + ks * 32 + quad * 8]);
#pragma unroll
            for (int dt = 0; dt < 4; ++dt) {
                bf16x8 vf = *reinterpret_cast<const bf16x8*>(
                    &Vt[(dt * 16 + l16) * LDSP + ks * 32 + quad * 8]);
                oacc[dt] = __builtin_amdgcn_mfma_f32_16x16x32_bf16(pf, vf, oacc[dt], 0, 0, 0);
            }
        }
        __syncthreads();
    }

    // normalize + store to o_flat [b*2304+row, h*64+d] bf16
#pragma unroll
    for (int dt = 0; dt < 4; ++dt)
#pragma unroll
        for (int rg = 0; rg < 4; ++rg) {
            float v = oacc[dt][rg] / l_i[rg];
            int row = q0 + wave * 16 + quad * 4 + rg;
            int col = h * HD + dt * 16 + l16;
            ob[((size_t)b * NSEQ + row) * DIM + col] = f2bf(v);
        }
}

// ---------------- proj GEMM: [4608,768] x [768,768]^T + bias -> fp32 out ----------------
__global__ __launch_bounds__(256) void gemm_proj_kernel(
    const short* __restrict__ A,    // ob [4608,768]
    const short* __restrict__ Bt,   // wprojb [768,768]
    const float* __restrict__ bias, // [768]
    float* __restrict__ out)
{
    __shared__ __align__(16) short At[64 * LDSP];
    __shared__ __align__(16) short Bl[64 * LDSP];
    const int m0 = blockIdx.x * 64, n0 = blockIdx.y * 64;
    const int tid = threadIdx.x, lane = tid & 63, wave = tid >> 6;
    const int quad = lane >> 4, l16 = lane & 15;
    const int wm = (wave >> 1) * 32, wn = (wave & 1) * 32;
    const int r = tid >> 2, cs = (tid & 3) * 16;
    f32x4 acc[2][2] = {};

    for (int k0 = 0; k0 < DIM; k0 += 64) {
        const uint4* ga = reinterpret_cast<const uint4*>(&A[(size_t)(m0 + r) * DIM + k0 + cs]);
        uint4* sa = reinterpret_cast<uint4*>(&At[r * LDSP + cs]);
        sa[0] = ga[0]; sa[1] = ga[1];
        const uint4* gb = reinterpret_cast<const uint4*>(&Bt[(size_t)(n0 + r) * DIM + k0 + cs]);
        uint4* sb = reinterpret_cast<uint4*>(&Bl[r * LDSP + cs]);
        sb[0] = gb[0]; sb[1] = gb[1];
        __syncthreads();
#pragma unroll
        for (int ks = 0; ks < 2; ++ks) {
            bf16x8 af[2], bf[2];
#pragma unroll
            for (int mt = 0; mt < 2; ++mt)
                af[mt] = *reinterpret_cast<const bf16x8*>(&At[(wm + mt * 16 + l16) * LDSP + ks * 32 + quad * 8]);
#pragma unroll
            for (int nt = 0; nt < 2; ++nt)
                bf[nt] = *reinterpret_cast<const bf16x8*>(&Bl[(wn + nt * 16 + l16) * LDSP + ks * 32 + quad * 8]);
#pragma unroll
            for (int mt = 0; mt < 2; ++mt)
#pragma unroll
                for (int nt = 0; nt < 2; ++nt)
                    acc[mt][nt] = __builtin_amdgcn_mfma_f32_16x16x32_bf16(af[mt], bf[nt], acc[mt][nt], 0, 0, 0);
        }
        __syncthreads();
    }

#pragma unroll
    for (int mt = 0; mt < 2; ++mt)
#pragma unroll
        for (int nt = 0; nt < 2; ++nt) {
            const int n = n0 + wn + nt * 16 + l16;
            const float bi = bias[n];
#pragma unroll
            for (int rg = 0; rg < 4; ++rg) {
                const int m = m0 + wm + mt * 16 + quad * 4 + rg;
                out[(size_t)m * DIM + n] = acc[mt][nt][rg] + bi;
            }
        }
}

extern "C" void kernel_launch(void* const* d_in, const int* in_sizes, int n_in,
                              void* d_out, int out_size, void* d_ws, size_t ws_size,
                              hipStream_t stream) {
    const float* x      = (const float*)d_in[0];
    const float* w_qkv  = (const float*)d_in[1];
    const float* b_qkv  = (const float*)d_in[2];
    const float* w_proj = (const float*)d_in[3];
    const float* b_proj = (const float*)d_in[4];
    float* out = (float*)d_out;

    short* xb     = (short*)d_ws;                       // 4608*768
    short* wqkvb  = xb + (size_t)M_TOK * DIM;           // 2304*768
    short* wprojb = wqkvb + (size_t)3 * DIM * DIM;      // 768*768
    short* qb     = wprojb + (size_t)DIM * DIM;         // 24*2304*64
    short* kb     = qb + (size_t)BATCH * HEADS * NSEQ * HD;
    short* vtb    = kb + (size_t)BATCH * HEADS * NSEQ * HD;
    short* ob     = vtb + (size_t)BATCH * HEADS * NSEQ * HD;

    // converts
    cvt_bf16_kernel<<<(M_TOK * DIM / 4 + 255) / 256, 256, 0, stream>>>(x, xb, M_TOK * DIM / 4);
    cvt_bf16_kernel<<<(3 * DIM * DIM / 4 + 255) / 256, 256, 0, stream>>>(w_qkv, wqkvb, 3 * DIM * DIM / 4);
    cvt_bf16_kernel<<<(DIM * DIM / 4 + 255) / 256, 256, 0, stream>>>(w_proj, wprojb, DIM * DIM / 4);

    // qkv GEMM + scatter
    dim3 g1(M_TOK / 64, 3 * DIM / 64);
    gemm_qkv_kernel<<<g1, 256, 0, stream>>>(xb, wqkvb, b_qkv, qb, kb, vtb);

    // RoPE
    int rope_n = BATCH * HEADS * NSEQ * 32;
    rope_kernel<<<(rope_n + 255) / 256, 256, 0, stream>>>(qb, kb);

    // attention
    dim3 g2(NSEQ / 64, HEADS, BATCH);
    attn_kernel<<<g2, 256, 0, stream>>>(qb, kb, vtb, ob);

    // proj GEMM
    dim3 g3(M_TOK / 64, DIM / 64);
    gemm_proj_kernel<<<g3, 256, 0, stream>>>(ob, wprojb, b_proj, out);
}

// Round 2
// 212.594 us; speedup vs baseline: 1.3157x; 1.3157x over previous
//
#include <hip/hip_runtime.h>

// Problem constants
#define BATCH 2
#define NSEQ 2304       // 48*48
#define DIM 768
#define HEADS 12
#define HD 64
#define M_TOK (BATCH * NSEQ)   // 4608
#define LDSP 72                // padded LDS row stride (bf16 elems): 144 B, 16B-aligned

typedef __attribute__((ext_vector_type(8))) short bf16x8;
typedef __attribute__((ext_vector_type(4))) float f32x4;

// softmax scale folded with log2(e): exp(x) = exp2(x * log2e)
#define QSCALE (0.125f * 1.44269504088896f)

__device__ __forceinline__ short f2bf(float f) {
    union { float f; unsigned u; } v; v.f = f;
    unsigned r = v.u + 0x7fffu + ((v.u >> 16) & 1u);
    return (short)(r >> 16);
}
__device__ __forceinline__ float bf2f(short s) {
    union { unsigned u; float f; } v; v.u = ((unsigned)(unsigned short)s) << 16;
    return v.f;
}

// ---------------- fp32 -> bf16 conversion (4 elems/thread) ----------------
__global__ void cvt_bf16_kernel(const float* __restrict__ in, short* __restrict__ out, int n4) {
    int i = blockIdx.x * 256 + threadIdx.x;
    if (i < n4) {
        float4 v = reinterpret_cast<const float4*>(in)[i];
        short4 o;
        o.x = f2bf(v.x); o.y = f2bf(v.y); o.z = f2bf(v.z); o.w = f2bf(v.w);
        reinterpret_cast<short4*>(out)[i] = o;
    }
}

// ---------------- qkv GEMM: [4608,768] x [2304,768]^T + bias ----------------
// scatters q,k -> [b,h,tok,d] bf16 ; v -> [b,h,d,tok] bf16 (transposed)
__global__ __launch_bounds__(256) void gemm_qkv_kernel(
    const short* __restrict__ A,    // xb [4608,768]
    const short* __restrict__ Bt,   // wqkvb [2304,768]
    const float* __restrict__ bias, // [2304]
    short* __restrict__ qb, short* __restrict__ kbuf, short* __restrict__ vtb)
{
    __shared__ __align__(16) short At[64 * LDSP];
    __shared__ __align__(16) short Bl[64 * LDSP];
    const int m0 = blockIdx.x * 64, n0 = blockIdx.y * 64;
    const int tid = threadIdx.x, lane = tid & 63, wave = tid >> 6;
    const int quad = lane >> 4, l16 = lane & 15;
    const int wm = (wave >> 1) * 32, wn = (wave & 1) * 32;
    const int r = tid >> 2, cs = (tid & 3) * 16;
    f32x4 acc[2][2] = {};

    for (int k0 = 0; k0 < DIM; k0 += 64) {
        const uint4* ga = reinterpret_cast<const uint4*>(&A[(size_t)(m0 + r) * DIM + k0 + cs]);
        uint4* sa = reinterpret_cast<uint4*>(&At[r * LDSP + cs]);
        sa[0] = ga[0]; sa[1] = ga[1];
        const uint4* gb = reinterpret_cast<const uint4*>(&Bt[(size_t)(n0 + r) * DIM + k0 + cs]);
        uint4* sb = reinterpret_cast<uint4*>(&Bl[r * LDSP + cs]);
        sb[0] = gb[0]; sb[1] = gb[1];
        __syncthreads();
#pragma unroll
        for (int ks = 0; ks < 2; ++ks) {
            bf16x8 af[2], bf[2];
#pragma unroll
            for (int mt = 0; mt < 2; ++mt)
                af[mt] = *reinterpret_cast<const bf16x8*>(&At[(wm + mt * 16 + l16) * LDSP + ks * 32 + quad * 8]);
#pragma unroll
            for (int nt = 0; nt < 2; ++nt)
                bf[nt] = *reinterpret_cast<const bf16x8*>(&Bl[(wn + nt * 16 + l16) * LDSP + ks * 32 + quad * 8]);
#pragma unroll
            for (int mt = 0; mt < 2; ++mt)
#pragma unroll
                for (int nt = 0; nt < 2; ++nt)
                    acc[mt][nt] = __builtin_amdgcn_mfma_f32_16x16x32_bf16(af[mt], bf[nt], acc[mt][nt], 0, 0, 0);
        }
        __syncthreads();
    }

    const int which = n0 / DIM;          // 0=q 1=k 2=v
    const int head = (n0 % DIM) / HD;
    const int b = m0 / NSEQ;             // NSEQ % 64 == 0 -> constant per block
    const int tokb = m0 % NSEQ;
#pragma unroll
    for (int mt = 0; mt < 2; ++mt) {
#pragma unroll
        for (int nt = 0; nt < 2; ++nt) {
            const int n = n0 + wn + nt * 16 + l16;
            const int d = wn + nt * 16 + l16;
            const float bi = bias[n];
            const int tok0 = tokb + wm + mt * 16 + quad * 4;
            if (which == 2) {
                short4 pv;
                pv.x = f2bf(acc[mt][nt][0] + bi);
                pv.y = f2bf(acc[mt][nt][1] + bi);
                pv.z = f2bf(acc[mt][nt][2] + bi);
                pv.w = f2bf(acc[mt][nt][3] + bi);
                *reinterpret_cast<short4*>(&vtb[((size_t)(b * HEADS + head) * HD + d) * NSEQ + tok0]) = pv;
            } else {
                short* dst = (which == 0) ? qb : kbuf;
#pragma unroll
                for (int rg = 0; rg < 4; ++rg)
                    dst[((size_t)(b * HEADS + head) * NSEQ + tok0 + rg) * HD + d] =
                        f2bf(acc[mt][nt][rg] + bi);
            }
        }
    }
}

// ---------------- RoPE in-place on q,k [bh, tok, 64] ----------------
// q additionally pre-scaled by QSCALE (softmax scale * log2e, folded into logits)
__global__ void rope_kernel(short* __restrict__ qb, short* __restrict__ kb) {
    int idx = blockIdx.x * 256 + threadIdx.x;  // total 24*2304*32
    if (idx >= BATCH * HEADS * NSEQ * 32) return;
    const int i = idx & 31;
    const int tok = (idx >> 5) % NSEQ;
    const int bh = idx / (32 * NSEQ);
    const int y = tok / 48, x = tok % 48;
    const int pi = (i < 16) ? i : (i - 16);
    const float coord = (i < 16) ? (2.0f * (y + 0.5f) / 48.0f - 1.0f)
                                 : (2.0f * (x + 0.5f) / 48.0f - 1.0f);
    const float period = powf(100.0f, (float)pi * (1.0f / 16.0f));
    const float ang = 2.0f * 3.14159265358979323846f * coord / period;
    const float s = sinf(ang), c = cosf(ang);
    const size_t base = ((size_t)bh * NSEQ + tok) * HD;
    float q1 = bf2f(qb[base + i]), q2 = bf2f(qb[base + i + 32]);
    qb[base + i]      = f2bf((q1 * c - q2 * s) * QSCALE);
    qb[base + i + 32] = f2bf((q2 * c + q1 * s) * QSCALE);
    float k1 = bf2f(kb[base + i]), k2 = bf2f(kb[base + i + 32]);
    kb[base + i]      = f2bf(k1 * c - k2 * s);
    kb[base + i + 32] = f2bf(k2 * c + k1 * s);
}

// ---------------- flash attention (no-max softmax, exp2 domain) ----------------
// grid (18, 12, 2), block 256. Each block: 128 q-rows for one (b,h); each wave 32 q-rows.
// K/V double-buffered via register staging: 1 barrier per k-tile.
// Row sums computed by MFMA against a constant all-ones B fragment (no shuffles).
__global__ __launch_bounds__(256) void attn_kernel(
    const short* __restrict__ qb, const short* __restrict__ kb,
    const short* __restrict__ vtb, short* __restrict__ ob)
{
    __shared__ __align__(16) short Kt[2][64 * LDSP];
    __shared__ __align__(16) short Vt[2][64 * LDSP];
    __shared__ __align__(16) short Pl[4][32 * LDSP];
    const int qt = blockIdx.x, h = blockIdx.y, b = blockIdx.z;
    const int bh = b * HEADS + h;
    const int tid = threadIdx.x, lane = tid & 63, wave = tid >> 6;
    const int quad = lane >> 4, l16 = lane & 15;
    const int qrow0 = qt * 128 + wave * 32;    // this wave's 32 q-rows
    const short* qbase = qb + (size_t)bh * NSEQ * HD;
    const short* kbase = kb + (size_t)bh * NSEQ * HD;
    const short* vbase = vtb + (size_t)bh * HD * NSEQ;

    // Q fragments (already scaled by QSCALE in rope)
    bf16x8 qf[2][2];
#pragma unroll
    for (int mt = 0; mt < 2; ++mt)
#pragma unroll
        for (int ks = 0; ks < 2; ++ks)
            qf[mt][ks] = *reinterpret_cast<const bf16x8*>(
                &qbase[(size_t)(qrow0 + mt * 16 + l16) * HD + ks * 32 + quad * 8]);

    bf16x8 ones;
#pragma unroll
    for (int i = 0; i < 8; ++i) ones[i] = (short)0x3F80;  // bf16 1.0

    f32x4 oacc[2][4] = {};
    f32x4 lacc[2] = {};

    const int r = tid >> 2, cs = (tid & 3) * 16;
    short* pw = Pl[wave];

    uint4 gk0, gk1, gv0, gv1;
    {
        const short* kp = &kbase[(size_t)r * HD + cs];
        gk0 = reinterpret_cast<const uint4*>(kp)[0];
        gk1 = reinterpret_cast<const uint4*>(kp)[1];
        const short* vp = &vbase[(size_t)r * NSEQ + cs];
        gv0 = reinterpret_cast<const uint4*>(vp)[0];
        gv1 = reinterpret_cast<const uint4*>(vp)[1];
        uint4* sk = reinterpret_cast<uint4*>(&Kt[0][r * LDSP + cs]);
        sk[0] = gk0; sk[1] = gk1;
        uint4* sv = reinterpret_cast<uint4*>(&Vt[0][r * LDSP + cs]);
        sv[0] = gv0; sv[1] = gv1;
    }

    int cur = 0;
    const int NT = NSEQ / 64;   // 36
    for (int kt = 0; kt < NT; ++kt) {
        if (kt + 1 < NT) {
            const short* kp = &kbase[(size_t)((kt + 1) * 64 + r) * HD + cs];
            gk0 = reinterpret_cast<const uint4*>(kp)[0];
            gk1 = reinterpret_cast<const uint4*>(kp)[1];
            const short* vp = &vbase[(size_t)r * NSEQ + (kt + 1) * 64 + cs];
            gv0 = reinterpret_cast<const uint4*>(vp)[0];
            gv1 = reinterpret_cast<const uint4*>(vp)[1];
        }
        __syncthreads();   // buf[cur] staged (prev iter's stores / prologue)

        // S = Q K^T : rows = mt*16+quad*4+rg, cols = nt*16+l16 (already in exp2 domain)
        f32x4 sacc[2][4] = {};
#pragma unroll
        for (int ks = 0; ks < 2; ++ks) {
#pragma unroll
            for (int nt = 0; nt < 4; ++nt) {
                bf16x8 kf = *reinterpret_cast<const bf16x8*>(
                    &Kt[cur][(nt * 16 + l16) * LDSP + ks * 32 + quad * 8]);
#pragma unroll
                for (int mt = 0; mt < 2; ++mt)
                    sacc[mt][nt] = __builtin_amdgcn_mfma_f32_16x16x32_bf16(qf[mt][ks], kf, sacc[mt][nt], 0, 0, 0);
            }
        }

        // P = exp2(S) -> LDS (C-layout -> A-layout round trip, wave-private)
#pragma unroll
        for (int mt = 0; mt < 2; ++mt)
#pragma unroll
            for (int nt = 0; nt < 4; ++nt)
#pragma unroll
                for (int rg = 0; rg < 4; ++rg)
                    pw[(mt * 16 + quad * 4 + rg) * LDSP + nt * 16 + l16] =
                        f2bf(__builtin_amdgcn_exp2f(sacc[mt][nt][rg]));

        // O += P V ; l += P * ones  (no barrier: P region is wave-private)
#pragma unroll
        for (int ks = 0; ks < 2; ++ks) {
            bf16x8 pf[2];
#pragma unroll
            for (int mt = 0; mt < 2; ++mt)
                pf[mt] = *reinterpret_cast<const bf16x8*>(
                    &pw[(mt * 16 + l16) * LDSP + ks * 32 + quad * 8]);
#pragma unroll
            for (int mt = 0; mt < 2; ++mt)
                lacc[mt] = __builtin_amdgcn_mfma_f32_16x16x32_bf16(pf[mt], ones, lacc[mt], 0, 0, 0);
#pragma unroll
            for (int dt = 0; dt < 4; ++dt) {
                bf16x8 vf = *reinterpret_cast<const bf16x8*>(
                    &Vt[cur][(dt * 16 + l16) * LDSP + ks * 32 + quad * 8]);
#pragma unroll
                for (int mt = 0; mt < 2; ++mt)
                    oacc[mt][dt] = __builtin_amdgcn_mfma_f32_16x16x32_bf16(pf[mt], vf, oacc[mt][dt], 0, 0, 0);
            }
        }

        if (kt + 1 < NT) {   // stage next tile into the other buffer
            uint4* sk = reinterpret_cast<uint4*>(&Kt[cur ^ 1][r * LDSP + cs]);
            sk[0] = gk0; sk[1] = gk1;
            uint4* sv = reinterpret_cast<uint4*>(&Vt[cur ^ 1][r * LDSP + cs]);
            sv[0] = gv0; sv[1] = gv1;
        }
        cur ^= 1;
    }

    // normalize + store to o_flat [b*2304+row, h*64+d] bf16
#pragma unroll
    for (int mt = 0; mt < 2; ++mt) {
        float inv[4];
#pragma unroll
        for (int rg = 0; rg < 4; ++rg) inv[rg] = __builtin_amdgcn_rcpf(lacc[mt][rg]);
#pragma unroll
        for (int dt = 0; dt < 4; ++dt)
#pragma unroll
            for (int rg = 0; rg < 4; ++rg) {
                int row = qrow0 + mt * 16 + quad * 4 + rg;
                int col = h * HD + dt * 16 + l16;
                ob[((size_t)b * NSEQ + row) * DIM + col] = f2bf(oacc[mt][dt][rg] * inv[rg]);
            }
    }
}

// ---------------- proj GEMM: [4608,768] x [768,768]^T + bias -> fp32 out ----------------
__global__ __launch_bounds__(256) void gemm_proj_kernel(
    const short* __restrict__ A,    // ob [4608,768]
    const short* __restrict__ Bt,   // wprojb [768,768]
    const float* __restrict__ bias, // [768]
    float* __restrict__ out)
{
    __shared__ __align__(16) short At[64 * LDSP];
    __shared__ __align__(16) short Bl[64 * LDSP];
    const int m0 = blockIdx.x * 64, n0 = blockIdx.y * 64;
    const int tid = threadIdx.x, lane = tid & 63, wave = tid >> 6;
    const int quad = lane >> 4, l16 = lane & 15;
    const int wm = (wave >> 1) * 32, wn = (wave & 1) * 32;
    const int r = tid >> 2, cs = (tid & 3) * 16;
    f32x4 acc[2][2] = {};

    for (int k0 = 0; k0 < DIM; k0 += 64) {
        const uint4* ga = reinterpret_cast<const uint4*>(&A[(size_t)(m0 + r) * DIM + k0 + cs]);
        uint4* sa = reinterpret_cast<uint4*>(&At[r * LDSP + cs]);
        sa[0] = ga[0]; sa[1] = ga[1];
        const uint4* gb = reinterpret_cast<const uint4*>(&Bt[(size_t)(n0 + r) * DIM + k0 + cs]);
        uint4* sb = reinterpret_cast<uint4*>(&Bl[r * LDSP + cs]);
        sb[0] = gb[0]; sb[1] = gb[1];
        __syncthreads();
#pragma unroll
        for (int ks = 0; ks < 2; ++ks) {
            bf16x8 af[2], bf[2];
#pragma unroll
            for (int mt = 0; mt < 2; ++mt)
                af[mt] = *reinterpret_cast<const bf16x8*>(&At[(wm + mt * 16 + l16) * LDSP + ks * 32 + quad * 8]);
#pragma unroll
            for (int nt = 0; nt < 2; ++nt)
                bf[nt] = *reinterpret_cast<const bf16x8*>(&Bl[(wn + nt * 16 + l16) * LDSP + ks * 32 + quad * 8]);
#pragma unroll
            for (int mt = 0; mt < 2; ++mt)
#pragma unroll
                for (int nt = 0; nt < 2; ++nt)
                    acc[mt][nt] = __builtin_amdgcn_mfma_f32_16x16x32_bf16(af[mt], bf[nt], acc[mt][nt], 0, 0, 0);
        }
        __syncthreads();
    }

#pragma unroll
    for (int mt = 0; mt < 2; ++mt)
#pragma unroll
        for (int nt = 0; nt < 2; ++nt) {
            const int n = n0 + wn + nt * 16 + l16;
            const float bi = bias[n];
#pragma unroll
            for (int rg = 0; rg < 4; ++rg) {
                const int m = m0 + wm + mt * 16 + quad * 4 + rg;
                out[(size_t)m * DIM + n] = acc[mt][nt][rg] + bi;
            }
        }
}

extern "C" void kernel_launch(void* const* d_in, const int* in_sizes, int n_in,
                              void* d_out, int out_size, void* d_ws, size_t ws_size,
                              hipStream_t stream) {
    const float* x      = (const float*)d_in[0];
    const float* w_qkv  = (const float*)d_in[1];
    const float* b_qkv  = (const float*)d_in[2];
    const float* w_proj = (const float*)d_in[3];
    const float* b_proj = (const float*)d_in[4];
    float* out = (float*)d_out;

    short* xb     = (short*)d_ws;                       // 4608*768
    short* wqkvb  = xb + (size_t)M_TOK * DIM;           // 2304*768
    short* wprojb = wqkvb + (size_t)3 * DIM * DIM;      // 768*768
    short* qb     = wprojb + (size_t)DIM * DIM;         // 24*2304*64
    short* kb     = qb + (size_t)BATCH * HEADS * NSEQ * HD;
    short* vtb    = kb + (size_t)BATCH * HEADS * NSEQ * HD;
    short* ob     = vtb + (size_t)BATCH * HEADS * NSEQ * HD;

    // converts
    cvt_bf16_kernel<<<(M_TOK * DIM / 4 + 255) / 256, 256, 0, stream>>>(x, xb, M_TOK * DIM / 4);
    cvt_bf16_kernel<<<(3 * DIM * DIM / 4 + 255) / 256, 256, 0, stream>>>(w_qkv, wqkvb, 3 * DIM * DIM / 4);
    cvt_bf16_kernel<<<(DIM * DIM / 4 + 255) / 256, 256, 0, stream>>>(w_proj, wprojb, DIM * DIM / 4);

    // qkv GEMM + scatter
    dim3 g1(M_TOK / 64, 3 * DIM / 64);
    gemm_qkv_kernel<<<g1, 256, 0, stream>>>(xb, wqkvb, b_qkv, qb, kb, vtb);

    // RoPE (+ Q prescale for exp2-domain softmax)
    int rope_n = BATCH * HEADS * NSEQ * 32;
    rope_kernel<<<(rope_n + 255) / 256, 256, 0, stream>>>(qb, kb);

    // attention
    dim3 g2(NSEQ / 128, HEADS, BATCH);
    attn_kernel<<<g2, 256, 0, stream>>>(qb, kb, vtb, ob);

    // proj GEMM
    dim3 g3(M_TOK / 64, DIM / 64);
    gemm_proj_kernel<<<g3, 256, 0, stream>>>(ob, wprojb, b_proj, out);
}